// Round 6
// baseline (158.410 us; speedup 1.0000x reference)
//
#include <hip/hip_runtime.h>

// DeepSets fused kernel for MI355X (gfx950) — round 6.
// r5 result: phi 85.8us, LDS-read bound (8-way duplicated data reads); tail ~30us.
// This round: (1) 2-row x 4-col wave split -> data LDS reads halved, weights
// doubled in VGPRs (w2=128 regs, pinned; biases moved to LDS to fit);
// (2) tail kernel 1024-thread split-K + L3 pre-warm of rho/head weights in prep.

typedef unsigned short u16;
typedef _Float16 f16x8 __attribute__((ext_vector_type(8)));
typedef _Float16 f16x4 __attribute__((ext_vector_type(4)));
typedef float f32x4 __attribute__((ext_vector_type(4)));
typedef int i32x4 __attribute__((ext_vector_type(4)));

#define NBLK 256

// ---------------- prep: fp32 weights -> fp16 fragments, zero gsum, warm L3 ---
// Fragment layout (validated r1-r5): lane l, elem j holds W[k=32*ks+8*(l>>4)+j][16*ctg+(l&15)]
// at frag[((ctg*KS+ks)*64 + l)*8 + j]. Used as MFMA *A* operand: D = W^T X^T = (XW)^T.
__global__ void prep_kernel(const float* __restrict__ pw1, const float* __restrict__ pw2,
                            _Float16* __restrict__ w1f, _Float16* __restrict__ w2f,
                            float* __restrict__ gsum,
                            const float* __restrict__ pw3, const float* __restrict__ rw1,
                            const float* __restrict__ rw2, const float* __restrict__ rw3,
                            const float* __restrict__ hw1, const float* __restrict__ hw2,
                            const float* __restrict__ hw3) {
    int idx = blockIdx.x * blockDim.x + threadIdx.x;   // 160*512 = 81920
    if (idx < 256) gsum[idx] = 0.f;
    if (idx < 16384) {  // pw1: 64x256, KS=2
        int j = idx & 7, l = (idx >> 3) & 63, ks = (idx >> 9) & 1, ct = idx >> 10;
        int k = 32 * ks + 8 * (l >> 4) + j;
        int col = 16 * ct + (l & 15);
        w1f[idx] = (_Float16)pw1[k * 256 + col];
    } else {            // pw2: 256x256, KS=8
        int o = idx - 16384;
        int j = o & 7, l = (o >> 3) & 63, ks = (o >> 9) & 7, ct = o >> 12;
        int k = 32 * ks + 8 * (l >> 4) + j;
        int col = 16 * ct + (l & 15);
        w2f[o] = (_Float16)pw2[k * 256 + col];
    }
    // ---- warm rho/head weights into L3 so tail_kernel doesn't stream cold HBM.
    float s = 0.f;
    if (idx < 32768) s += pw3[idx];
    if (idx < 32768) s += rw1[idx];
    if (idx < 65536) s += rw2[idx];
    if (idx < 32768) s += rw3[idx];
    if (idx < 36864) s += hw1[idx];
    if (idx < 65536) s += hw2[idx];
    if (idx < 1280)  s += hw3[idx];
    asm volatile("" :: "v"(s));   // keep loads live, no memory side effects
}

__device__ __forceinline__ void pin_reg(f16x8& v) {
    i32x4 t = __builtin_bit_cast(i32x4, v);
    asm volatile("" : "+v"(t));
    v = __builtin_bit_cast(f16x8, t);
}

// ---------------- fused phi + pool (persistent) ------------------------------
// 8 waves: rg = w>>2 owns rows [32rg,32rg+32); cg = w&3 owns cols [64cg,64cg+64).
__global__ __attribute__((amdgpu_flat_work_group_size(512, 512), amdgpu_waves_per_eu(2, 2)))
void phi_kernel(
    const float* __restrict__ x,
    const float* __restrict__ pb1, const float* __restrict__ pb2,
    const _Float16* __restrict__ w1g, const _Float16* __restrict__ w2g,
    float* __restrict__ gsum, int ntiles) {
    __shared__ __align__(16) u16 xs[2][64 * 64];    // x tile fp16, swz ^((row&7)<<4)
    __shared__ __align__(16) u16 h1s[2][64 * 256];  // h1 tile fp16, swz ^((row&15)<<4)
    __shared__ __align__(16) float b1s[256], b2s[256];

    const int tid = threadIdx.x;
    const int l = tid & 63;
    const int w = tid >> 6;
    const int fr = l & 15;
    const int fg = l >> 4;
    const int rg = w >> 2;      // row group: rows [32rg, 32rg+32)
    const int cg = w & 3;       // col group: cols [64cg, 64cg+64)

    // biases to LDS (frees 32 VGPRs vs r5)
    if (tid < 256) b1s[tid] = pb1[tid];
    else if (tid < 512) b2s[tid - 256] = pb2[tid - 256];

    // ---- preload weight fragments into registers (loop-invariant, pinned)
    f16x8 w1r[4][2];   // [ct][ks], ctg = 4*cg + ct
    f16x8 w2r[4][8];
#pragma unroll
    for (int ct = 0; ct < 4; ++ct) {
        int ctg = 4 * cg + ct;
#pragma unroll
        for (int ks = 0; ks < 2; ++ks)
            w1r[ct][ks] = *(const f16x8*)(w1g + (((ctg << 1) + ks) << 9) + (l << 3));
#pragma unroll
        for (int ks = 0; ks < 8; ++ks)
            w2r[ct][ks] = *(const f16x8*)(w2g + (((ctg << 3) + ks) << 9) + (l << 3));
    }
#pragma unroll
    for (int ct = 0; ct < 4; ++ct) {
#pragma unroll
        for (int ks = 0; ks < 2; ++ks) pin_reg(w1r[ct][ks]);
#pragma unroll
        for (int ks = 0; ks < 8; ++ks) pin_reg(w2r[ct][ks]);
    }

    float psum[4][4] = {};

    const int t0 = blockIdx.x;
    // ---- prologue: stage tile t0 into xs[0], prefetch t0+NBLK into regs
    {
        const float4* xg = (const float4*)(x + (size_t)t0 * 4096);
#pragma unroll
        for (int i = 0; i < 2; ++i) {
            int f4 = tid + i * 512;
            float4 v = xg[f4];
            int row = f4 >> 4, c4 = f4 & 15;
            f16x4 b;
            b[0] = (_Float16)v.x; b[1] = (_Float16)v.y;
            b[2] = (_Float16)v.z; b[3] = (_Float16)v.w;
            int byte = (row * 128 + c4 * 8) ^ ((row & 7) << 4);
            *(f16x4*)((char*)xs[0] + byte) = b;
        }
    }
    float4 pf0, pf1;
    {
        int tn = (t0 + NBLK < ntiles) ? t0 + NBLK : 0;
        const float4* xg = (const float4*)(x + (size_t)tn * 4096);
        pf0 = xg[tid];
        pf1 = xg[tid + 512];
    }
    __syncthreads();

    int buf = 0, hb = 0;
    for (int t = t0; t < ntiles; t += NBLK) {
        // ---- GEMM1: D1 = (x@pw1)^T from xs[buf]; wave: 64 cols x 32 rows
        {
            f32x4 acc[4][2] = {};
#pragma unroll
            for (int ks = 0; ks < 2; ++ks) {
                f16x8 bd[2];
#pragma unroll
                for (int rtl = 0; rtl < 2; ++rtl) {
                    int row = ((2 * rg + rtl) << 4) + fr;
                    int byte = ((row << 7) + (ks << 6) + (fg << 4)) ^ ((row & 7) << 4);
                    bd[rtl] = *(const f16x8*)((char*)xs[buf] + byte);
                }
#pragma unroll
                for (int ct = 0; ct < 4; ++ct)
#pragma unroll
                    for (int rtl = 0; rtl < 2; ++rtl)
                        acc[ct][rtl] = __builtin_amdgcn_mfma_f32_16x16x32_f16(w1r[ct][ks], bd[rtl], acc[ct][rtl], 0, 0, 0);
            }
            // epilogue: bias(+LDS)+relu; lane holds h-cols c0..c0+3 of row rown
#pragma unroll
            for (int ct = 0; ct < 4; ++ct) {
                int c0 = 64 * cg + 16 * ct + 4 * fg;
                f32x4 bb = *(const f32x4*)(b1s + c0);
#pragma unroll
                for (int rtl = 0; rtl < 2; ++rtl) {
                    int rown = ((2 * rg + rtl) << 4) + fr;
                    f16x4 o;
                    o[0] = (_Float16)fmaxf(acc[ct][rtl][0] + bb[0], 0.f);
                    o[1] = (_Float16)fmaxf(acc[ct][rtl][1] + bb[1], 0.f);
                    o[2] = (_Float16)fmaxf(acc[ct][rtl][2] + bb[2], 0.f);
                    o[3] = (_Float16)fmaxf(acc[ct][rtl][3] + bb[3], 0.f);
                    int byte = ((rown << 9) + (c0 << 1)) ^ ((rown & 15) << 4);
                    *(f16x4*)((char*)h1s[hb] + byte) = o;
                }
            }
        }
        // ---- stage next x tile (regs -> xs[buf^1]); prefetch t+2*NBLK
#pragma unroll
        for (int i = 0; i < 2; ++i) {
            float4 v = i ? pf1 : pf0;
            int f4 = tid + i * 512;
            int row = f4 >> 4, c4 = f4 & 15;
            f16x4 b;
            b[0] = (_Float16)v.x; b[1] = (_Float16)v.y;
            b[2] = (_Float16)v.z; b[3] = (_Float16)v.w;
            int byte = (row * 128 + c4 * 8) ^ ((row & 7) << 4);
            *(f16x4*)((char*)xs[buf ^ 1] + byte) = b;
        }
        {
            int tn = (t + 2 * NBLK < ntiles) ? t + 2 * NBLK : 0;
            const float4* xg = (const float4*)(x + (size_t)tn * 4096);
            pf0 = xg[tid];
            pf1 = xg[tid + 512];
        }
        __syncthreads();   // h1s[hb] + xs[buf^1] now visible

        // ---- GEMM2: D2 = (h1@pw2)^T, pool into psum
        {
            f32x4 acc2[4][2] = {};
#pragma unroll
            for (int ks = 0; ks < 8; ++ks) {
                f16x8 bd[2];
#pragma unroll
                for (int rtl = 0; rtl < 2; ++rtl) {
                    int row = ((2 * rg + rtl) << 4) + fr;
                    int byte = ((row << 9) + (ks << 6) + (fg << 4)) ^ ((row & 15) << 4);
                    bd[rtl] = *(const f16x8*)((char*)h1s[hb] + byte);
                }
#pragma unroll
                for (int ct = 0; ct < 4; ++ct)
#pragma unroll
                    for (int rtl = 0; rtl < 2; ++rtl)
                        acc2[ct][rtl] = __builtin_amdgcn_mfma_f32_16x16x32_f16(w2r[ct][ks], bd[rtl], acc2[ct][rtl], 0, 0, 0);
            }
#pragma unroll
            for (int ct = 0; ct < 4; ++ct) {
                int c0 = 64 * cg + 16 * ct + 4 * fg;
                f32x4 bb = *(const f32x4*)(b2s + c0);
#pragma unroll
                for (int r = 0; r < 4; ++r) {
                    float v = fmaxf(acc2[ct][0][r] + bb[r], 0.f) + fmaxf(acc2[ct][1][r] + bb[r], 0.f);
                    psum[ct][r] += v;
                }
            }
        }
        buf ^= 1;
        hb ^= 1;
    }

    // ---- final: reduce psum over the 16 fr-lanes, one atomicAdd per col
#pragma unroll
    for (int ct = 0; ct < 4; ++ct)
#pragma unroll
        for (int r = 0; r < 4; ++r) {
            float v = psum[ct][r];
            v += __shfl_xor(v, 1, 64);
            v += __shfl_xor(v, 2, 64);
            v += __shfl_xor(v, 4, 64);
            v += __shfl_xor(v, 8, 64);
            if (fr == 0) atomicAdd(&gsum[64 * cg + 16 * ct + 4 * fg + r], v);
        }
}

// ---------------- tail: split-K parallel rho + head (fp32, 1024 threads) ----
__global__ __launch_bounds__(1024) void tail_kernel(
    const float* __restrict__ gsum, const float* __restrict__ xst,
    const float* __restrict__ pw3, const float* __restrict__ pb3,
    const float* __restrict__ rw1, const float* __restrict__ rb1,
    const float* __restrict__ rw2, const float* __restrict__ rb2,
    const float* __restrict__ rw3, const float* __restrict__ rb3,
    const float* __restrict__ w1, const float* __restrict__ b1,
    const float* __restrict__ w2, const float* __restrict__ b2,
    const float* __restrict__ w3, const float* __restrict__ b3,
    float* __restrict__ out, float nf) {
    __shared__ float fp[128], r1[256], r2[256], tc[144], t1[256], t2[256];
    __shared__ float part[8][256];
    const int t = threadIdx.x;

    // L0: fp = nf*pb3 + gsum @ pw3  (IN=256, OUT=128, 8-way split)
    {
        int j = t & 127, q = t >> 7;
        float s = 0.f;
        for (int i = 32 * q; i < 32 * q + 32; ++i) s += gsum[i] * pw3[i * 128 + j];
        part[q][j] = s;
    }
    __syncthreads();
    if (t < 128) { float s = nf * pb3[t]; for (int q = 0; q < 8; ++q) s += part[q][t]; fp[t] = s; }
    __syncthreads();
    // r1 = relu(fp @ rw1 + rb1)  (IN=128, OUT=256, 4-way)
    {
        int j = t & 255, q = t >> 8;
        float s = 0.f;
        for (int i = 32 * q; i < 32 * q + 32; ++i) s += fp[i] * rw1[i * 256 + j];
        part[q][j] = s;
    }
    __syncthreads();
    if (t < 256) { float s = rb1[t]; for (int q = 0; q < 4; ++q) s += part[q][t]; r1[t] = fmaxf(s, 0.f); }
    __syncthreads();
    // r2 = relu(r1 @ rw2 + rb2)  (IN=256, OUT=256, 4-way)
    {
        int j = t & 255, q = t >> 8;
        float s = 0.f;
        for (int i = 64 * q; i < 64 * q + 64; ++i) s += r1[i] * rw2[i * 256 + j];
        part[q][j] = s;
    }
    __syncthreads();
    if (t < 256) { float s = rb2[t]; for (int q = 0; q < 4; ++q) s += part[q][t]; r2[t] = fmaxf(s, 0.f); }
    __syncthreads();
    // tc[0:128] = r2 @ rw3 + rb3  (IN=256, OUT=128, 8-way); tc[128:144] = xst
    {
        int j = t & 127, q = t >> 7;
        float s = 0.f;
        for (int i = 32 * q; i < 32 * q + 32; ++i) s += r2[i] * rw3[i * 128 + j];
        part[q][j] = s;
    }
    __syncthreads();
    if (t < 128) { float s = rb3[t]; for (int q = 0; q < 8; ++q) s += part[q][t]; tc[t] = s; }
    else if (t < 144) tc[t] = xst[t - 128];
    __syncthreads();
    // t1 = relu(tc @ w1 + b1)  (IN=144, OUT=256, 4-way, 36 each)
    {
        int j = t & 255, q = t >> 8;
        float s = 0.f;
        for (int i = 36 * q; i < 36 * q + 36; ++i) s += tc[i] * w1[i * 256 + j];
        part[q][j] = s;
    }
    __syncthreads();
    if (t < 256) { float s = b1[t]; for (int q = 0; q < 4; ++q) s += part[q][t]; t1[t] = fmaxf(s, 0.f); }
    __syncthreads();
    // t2 = relu(t1 @ w2 + b2)  (IN=256, OUT=256, 4-way)
    {
        int j = t & 255, q = t >> 8;
        float s = 0.f;
        for (int i = 64 * q; i < 64 * q + 64; ++i) s += t1[i] * w2[i * 256 + j];
        part[q][j] = s;
    }
    __syncthreads();
    if (t < 256) { float s = b2[t]; for (int q = 0; q < 4; ++q) s += part[q][t]; t2[t] = fmaxf(s, 0.f); }
    __syncthreads();
    // out = t2 @ w3 + b3  (IN=256, OUT=5, 4-way)
    {
        int j = t & 255, q = t >> 8;
        if (j < 5) {
            float s = 0.f;
            for (int i = 64 * q; i < 64 * q + 64; ++i) s += t2[i] * w3[i * 5 + j];
            part[q][j] = s;
        }
    }
    __syncthreads();
    if (t < 5) { float s = b3[t]; for (int q = 0; q < 4; ++q) s += part[q][t]; out[t] = s; }
}

extern "C" void kernel_launch(void* const* d_in, const int* in_sizes, int n_in,
                              void* d_out, int out_size, void* d_ws, size_t ws_size,
                              hipStream_t stream) {
    (void)n_in; (void)out_size; (void)ws_size;
    const float* x   = (const float*)d_in[0];
    const float* xst = (const float*)d_in[1];
    const float* pw1 = (const float*)d_in[2];
    const float* pb1 = (const float*)d_in[3];
    const float* pw2 = (const float*)d_in[4];
    const float* pb2 = (const float*)d_in[5];
    const float* pw3 = (const float*)d_in[6];
    const float* pb3 = (const float*)d_in[7];
    const float* rw1 = (const float*)d_in[8];
    const float* rb1 = (const float*)d_in[9];
    const float* rw2 = (const float*)d_in[10];
    const float* rb2 = (const float*)d_in[11];
    const float* rw3 = (const float*)d_in[12];
    const float* rb3 = (const float*)d_in[13];
    const float* w1  = (const float*)d_in[14];
    const float* b1  = (const float*)d_in[15];
    const float* w2  = (const float*)d_in[16];
    const float* b2  = (const float*)d_in[17];
    const float* w3  = (const float*)d_in[18];
    const float* b3  = (const float*)d_in[19];
    float* out = (float*)d_out;

    int n = in_sizes[0] / 64;      // 400000
    int ntiles = n >> 6;           // 6250 (exact)

    char* ws = (char*)d_ws;
    float* gsum = (float*)ws;                       // 256 f32 (1KB)
    _Float16* w1f = (_Float16*)(ws + 1024);         // 16384 f16 (32KB)
    _Float16* w2f = (_Float16*)(ws + 1024 + 32768); // 65536 f16 (128KB)

    prep_kernel<<<160, 512, 0, stream>>>(pw1, pw2, w1f, w2f, gsum,
                                         pw3, rw1, rw2, rw3, w1, w2, w3);
    phi_kernel<<<NBLK, 512, 0, stream>>>(x, pb1, pb2, w1f, w2f, gsum, ntiles);
    tail_kernel<<<1, 1024, 0, stream>>>(gsum, xst, pw3, pb3, rw1, rb1, rw2, rb2,
                                        rw3, rb3, w1, b1, w2, b2, w3, b3, out, (float)n);
}